// Round 3
// baseline (864.415 us; speedup 1.0000x reference)
//
#include <hip/hip_runtime.h>
#include <math.h>

// ---------------- workspace layout ----------------
static const size_t OFF_TW = 0;
static const size_t OFF_V  = 32768;
static const size_t OFF_AT = OFF_V  + (size_t)16 * 64 * 4104 * 8;
static const size_t OFF_ZX = OFF_AT + (size_t)16 * 32 * 8192 * 8;
static const size_t WS_NEED = OFF_ZX + (size_t)128 * 32 * 4096 * 8;

// ---------------- twiddle init ----------------
__global__ void __launch_bounds__(256) k_init_tw(float2* __restrict__ tw)
{
    int k = blockIdx.x * 256 + threadIdx.x;
    if (k < 4096) {
        double a = (double)k * (3.14159265358979323846 / 4096.0);
        tw[k] = make_float2((float)cos(a), (float)(-sin(a)));
    }
}

// ---------------- dpb MLP: lane per evaluation row ----------------
// All loops that index the per-thread arrays are FULLY unrolled so every
// array access has a compile-time index -> arrays live in VGPRs, not scratch.
__device__ __forceinline__ void ln_relu_arr(float* b,
                                            const float* __restrict__ g,
                                            const float* __restrict__ be)
{
    float s0 = 0, s1 = 0, s2 = 0, s3 = 0;
    #pragma unroll
    for (int k = 0; k < 64; k += 4) {
        s0 += b[k]; s1 += b[k + 1]; s2 += b[k + 2]; s3 += b[k + 3];
    }
    float m = (s0 + s1 + s2 + s3) * (1.0f / 64.0f);
    float v0 = 0, v1 = 0, v2 = 0, v3 = 0;
    #pragma unroll
    for (int k = 0; k < 64; k += 4) {
        float c0 = b[k] - m, c1 = b[k + 1] - m, c2 = b[k + 2] - m, c3 = b[k + 3] - m;
        v0 = fmaf(c0, c0, v0); v1 = fmaf(c1, c1, v1);
        v2 = fmaf(c2, c2, v2); v3 = fmaf(c3, c3, v3);
    }
    float inv = rsqrtf((v0 + v1 + v2 + v3) * (1.0f / 64.0f) + 1e-5f);
    #pragma unroll
    for (int k = 0; k < 64; ++k)
        b[k] = fmaxf(fmaf((b[k] - m) * inv, g[k], be[k]), 0.0f);
}

__device__ __forceinline__ void matmul64(const float* b, float* o,
                                         const float* __restrict__ w,
                                         const float* __restrict__ bias)
{
    #pragma unroll
    for (int j = 0; j < 64; ++j) o[j] = bias[j];
    #pragma unroll
    for (int k = 0; k < 64; ++k) {
        float bk = b[k];
        const float* wr = w + (k << 6);
        #pragma unroll
        for (int j = 0; j < 64; ++j) o[j] = fmaf(bk, wr[j], o[j]);
    }
}

__global__ void __launch_bounds__(256) k_dpb(
    const float* __restrict__ w0,  const float* __restrict__ b0,
    const float* __restrict__ g1,  const float* __restrict__ be1,
    const float* __restrict__ w1,  const float* __restrict__ b1,
    const float* __restrict__ g2,  const float* __restrict__ be2,
    const float* __restrict__ w2,  const float* __restrict__ b2,
    const float* __restrict__ g3,  const float* __restrict__ be3,
    const float* __restrict__ w3,  const float* __restrict__ b3,
    float* __restrict__ aTf)
{
    int e  = blockIdx.x * 256 + threadIdx.x;
    int r  = e & 8191;
    int dd = e >> 13;
    const float scale = (float)(1.0 / 262080.0);
    float u;
    if (r == 0 || r == 4096) u = 0.0f;
    else if (r < 4096)       u = (float)((r - 1) * 64 + dd + 1) * scale;
    else                     u = -(float)(262080 - ((r - 4097) * 64 + dd)) * scale;

    float b[64], o[64];
    #pragma unroll
    for (int j = 0; j < 64; ++j) b[j] = fmaf(u, w0[j], b0[j]);

    ln_relu_arr(b, g1, be1);
    matmul64(b, o, w1, b1);
    ln_relu_arr(o, g2, be2);
    matmul64(o, b, w2, b2);
    ln_relu_arr(b, g3, be3);

    float f[16];
    #pragma unroll
    for (int j = 0; j < 16; ++j) f[j] = b3[j];
    #pragma unroll
    for (int k = 0; k < 64; ++k) {
        float bk = b[k];
        const float* wr = w3 + (k << 4);
        #pragma unroll
        for (int j = 0; j < 16; ++j) f[j] = fmaf(bk, wr[j], f[j]);
    }
    #pragma unroll
    for (int h = 0; h < 16; ++h) {
        size_t idx = ((size_t)((h << 5) + (dd >> 1)) * 8192 + r) * 2 + (dd & 1);
        aTf[idx] = f[h];
    }
}

// ---------------- LDS swizzle for float2[8192] ----------------
// sw(p) = p ^ ((p>>4)&15) ^ ((p>>8)&1): involution on [0,8192); keeps every
// access pattern in the FFT (contiguous fill, bit-reversed gather, stride-16
// writeback, radix-16 stage strides 16/256, span-4096 radix-2, k<->8192-k
// pairing) at exactly 4 dwords/bank per wave64 ds_*_b64 == conflict-free.
__device__ __forceinline__ int sw(int a)
{
    return a ^ ((a >> 4) & 15) ^ ((a >> 8) & 1);
}

__device__ __forceinline__ float2 cmul(float2 a, float2 b)
{
    return make_float2(fmaf(a.x, b.x, -(a.y * b.y)), fmaf(a.x, b.y, a.y * b.x));
}

// multiply by forward twiddle (wr, wi); INV conjugates the twiddle
template<bool INV>
__device__ __forceinline__ float2 twm(float2 a, float wr, float wi)
{
    float i = INV ? -wi : wi;
    return make_float2(fmaf(a.x, wr, -(a.y * i)), fmaf(a.x, i, a.y * wr));
}

// ---------------- in-register 16-point DIT FFT ----------------
// input z in bit-reversed order, output natural order
template<bool INV>
__device__ __forceinline__ void fft16(float2* z)
{
    const float SQ = 0.70710678118654752440f;
    const float C1 = 0.92387953251128675613f;  // cos(pi/8)
    const float S1 = 0.38268343236508977173f;  // sin(pi/8)
    #pragma unroll
    for (int b = 0; b < 16; b += 2) {
        float2 u = z[b], t = z[b + 1];
        z[b]     = make_float2(u.x + t.x, u.y + t.y);
        z[b + 1] = make_float2(u.x - t.x, u.y - t.y);
    }
    const float w4r[2] = {1.0f, 0.0f};
    const float w4i[2] = {0.0f, -1.0f};
    #pragma unroll
    for (int b = 0; b < 16; b += 4) {
        #pragma unroll
        for (int j = 0; j < 2; ++j) {
            float2 u = z[b + j];
            float2 t = twm<INV>(z[b + j + 2], w4r[j], w4i[j]);
            z[b + j]     = make_float2(u.x + t.x, u.y + t.y);
            z[b + j + 2] = make_float2(u.x - t.x, u.y - t.y);
        }
    }
    const float w8r[4] = {1.0f, SQ, 0.0f, -SQ};
    const float w8i[4] = {0.0f, -SQ, -1.0f, -SQ};
    #pragma unroll
    for (int b = 0; b < 16; b += 8) {
        #pragma unroll
        for (int j = 0; j < 4; ++j) {
            float2 u = z[b + j];
            float2 t = twm<INV>(z[b + j + 4], w8r[j], w8i[j]);
            z[b + j]     = make_float2(u.x + t.x, u.y + t.y);
            z[b + j + 4] = make_float2(u.x - t.x, u.y - t.y);
        }
    }
    const float wgr[8] = {1.0f, C1, SQ, S1, 0.0f, -S1, -SQ, -C1};
    const float wgi[8] = {0.0f, -S1, -SQ, -C1, -1.0f, -C1, -SQ, -S1};
    #pragma unroll
    for (int j = 0; j < 8; ++j) {
        float2 u = z[j];
        float2 t = twm<INV>(z[j + 8], wgr[j], wgi[j]);
        z[j]     = make_float2(u.x + t.x, u.y + t.y);
        z[j + 8] = make_float2(u.x - t.x, u.y - t.y);
    }
}

// ---------------- radix-16 LDS butterfly ----------------
// Fuses 4 radix-2 DIT stages (spans L,2L,4L,8L):
//   out_q = sum_u v[rev4(u)] * W_{16L}^{j*u} * W_16^{q*u}
// tw index scale s must satisfy 16*L*s == 8192.
// (stage A: L=16, s=32; stage B: L=256, s=2)
// Register-pressure note: T[] is scoped to the gather phase and the swizzled
// addresses are recomputed at writeback, so peak live state ~ z[16] only.
template<bool INV>
__device__ __forceinline__ void r16(float2* __restrict__ Z, int base, int j, int L, int s,
                                    const float2* __restrict__ tw)
{
    const int rv[16] = {0, 8, 4, 12, 2, 10, 6, 14, 1, 9, 5, 13, 3, 11, 7, 15};
    float2 z[16];
    {
        float2 t1 = tw[j * s], t2 = tw[2 * j * s], t4 = tw[4 * j * s], t8 = tw[8 * j * s];
        if (INV) { t1.y = -t1.y; t2.y = -t2.y; t4.y = -t4.y; t8.y = -t8.y; }
        float2 T[16];
        T[1] = t1; T[2] = t2; T[4] = t4; T[8] = t8;
        T[3]  = cmul(t1, t2);   T[5]  = cmul(t1, t4);   T[6]  = cmul(t2, t4);
        T[7]  = cmul(T[3], t4); T[9]  = cmul(t1, t8);   T[10] = cmul(t2, t8);
        T[11] = cmul(T[3], t8); T[12] = cmul(t4, t8);   T[13] = cmul(T[5], t8);
        T[14] = cmul(T[6], t8); T[15] = cmul(T[7], t8);
        z[0] = Z[sw(base + j)];
        #pragma unroll
        for (int m = 1; m < 16; ++m) z[m] = cmul(Z[sw(base + j + L * m)], T[rv[m]]);
    }
    fft16<INV>(z);
    #pragma unroll
    for (int q = 0; q < 16; ++q) Z[sw(base + j + L * q)] = z[q];
}

// ---------------- first 4 stages in registers (16 pts/thread) ----------------
template<int L, bool INV>
__device__ __forceinline__ void reg_stage16(float* xr, float* xi,
                                            const float2* __restrict__ tw)
{
    #pragma unroll
    for (int b = 0; b < 16; b += 2 * L) {
        #pragma unroll
        for (int j = 0; j < L; ++j) {
            float2 w = tw[j * (4096 / L)];
            float wr = w.x, wi = INV ? -w.y : w.y;
            int i0 = b + j, i1 = b + j + L;
            float tr = xr[i1] * wr - xi[i1] * wi;
            float ti = xr[i1] * wi + xi[i1] * wr;
            xr[i1] = xr[i0] - tr; xi[i1] = xi[i0] - ti;
            xr[i0] += tr;         xi[i0] += ti;
        }
    }
}

// ---------------- 8192-pt complex FFT: natural in/out, 512 threads ----------
// 13 radix-2 stages = reg fft16 (spans 1..8) + r16(L=16) (16..128)
//                   + r16(L=256) (256..2048) + radix-2 (4096).
// Caller must __syncthreads() after populating Z and before calling.
template<bool INV>
__device__ __forceinline__ void fft8192_lds(float2* __restrict__ Z,
                                            const float2* __restrict__ tw)
{
    const int t  = threadIdx.x;                       // 512 threads
    const int r9 = (int)(__brev((unsigned)t) >> 23);  // rev9(t)
    float xr[16], xi[16];
    #pragma unroll
    for (int i = 0; i < 16; ++i) {
        int r4 = (int)(__brev((unsigned)i) >> 28);    // rev4(i)
        float2 v = Z[sw((r4 << 9) | r9)];             // rev13(16t+i)
        xr[i] = v.x; xi[i] = v.y;
    }
    __syncthreads();
    reg_stage16<1, INV>(xr, xi, tw);
    reg_stage16<2, INV>(xr, xi, tw);
    reg_stage16<4, INV>(xr, xi, tw);
    reg_stage16<8, INV>(xr, xi, tw);
    #pragma unroll
    for (int i = 0; i < 16; ++i) Z[sw(16 * t + i)] = make_float2(xr[i], xi[i]);
    __syncthreads();
    // stage A: spans 16..128, 32 groups of 256
    r16<INV>(Z, (t >> 4) * 256, t & 15, 16, 32, tw);
    __syncthreads();
    // stage B: spans 256..2048, 2 groups of 4096
    r16<INV>(Z, (t >> 8) * 4096, t & 255, 256, 2, tw);
    __syncthreads();
    // stage C: final radix-2, span 4096
    #pragma unroll
    for (int m = 0; m < 8; ++m) {
        int k = t + 512 * m;
        float2 w = tw[k];
        float wi = INV ? -w.y : w.y;
        int aL = sw(k), aH = sw(k + 4096);
        float2 u = Z[aL], v = Z[aH];
        float tr = fmaf(v.x, w.x, -(v.y * wi));
        float ti = fmaf(v.x, wi, v.y * w.x);
        Z[aL] = make_float2(u.x + tr, u.y + ti);
        Z[aH] = make_float2(u.x - tr, u.y - ti);
    }
    __syncthreads();
}

// ---------------- V = rfft(a) / 8192, d-pairs packed ----------------
// NOTE launch bounds: HIP/CUDA semantics -> 2nd arg is min BLOCKS per CU.
// (512,4) produced VGPR=64 (8 waves/EU cap) -> massive spills (+333 MB HBM).
// (512,2) -> 16 waves/CU cap -> VGPR cap 128, matching the 64 KiB LDS limit
// of 2 blocks/CU.
__global__ void __launch_bounds__(512, 2) k_vfft(const float2* __restrict__ aT,
                                                 const float2* __restrict__ tw,
                                                 float2* __restrict__ V)
{
    __shared__ float2 Z[8192];
    int blk = blockIdx.x;         // h*32 + p
    int h = blk >> 5, p = blk & 31;
    const float2* ac = aT + (size_t)(h * 32 + p) * 8192;
    int t = threadIdx.x;
    #pragma unroll
    for (int i = 0; i < 16; ++i) {
        int idx = i * 512 + t;
        Z[sw(idx)] = ac[idx];
    }
    __syncthreads();
    fft8192_lds<false>(Z, tw);
    const float s = 1.0f / 8192.0f;
    float2* V0 = V + (size_t)(h * 64 + 2 * p) * 4104;
    float2* V1 = V0 + 4104;
    for (int k = t; k <= 4096; k += 512) {
        int km = (8192 - k) & 8191;
        float2 z1 = Z[sw(k)], z2 = Z[sw(km)];
        float zr1 = z1.x, zi1 = z1.y;
        float zr2 = z2.x, zi2 = -z2.y;
        float a0r = 0.5f * (zr1 + zr2), a0i = 0.5f * (zi1 + zi2);
        float a1r = 0.5f * (zi1 - zi2), a1i = -0.5f * (zr1 - zr2);
        V0[k] = make_float2(a0r * s, a0i * s);
        V1[k] = make_float2(a1r * s, a1i * s);
    }
}

// ---------------- pack x: (b,h,r,d) -> float2[bh][p][r] ----------------
__global__ void __launch_bounds__(256) k_pack_x(const float* __restrict__ x,
                                                float2* __restrict__ zx)
{
    int blk = blockIdx.x;
    int bh = blk >> 7, rt = blk & 127, r0 = rt << 5;
    __shared__ float tile[64][33];
    const float* xp = x + (size_t)bh * 4096 * 64;
    int tid = threadIdx.x;
    #pragma unroll
    for (int i = 0; i < 8; ++i) {
        int idx = i * 256 + tid;
        int rr = idx >> 6, d = idx & 63;
        tile[d][rr] = xp[(size_t)(r0 + rr) * 64 + d];
    }
    __syncthreads();
    float2* zp = zx + (size_t)bh * 32 * 4096;
    #pragma unroll
    for (int i = 0; i < 4; ++i) {
        int idx = i * 256 + tid;
        int p = idx >> 5, rr = idx & 31;
        zp[(size_t)p * 4096 + r0 + rr] = make_float2(tile[2 * p][rr], tile[2 * p + 1][rr]);
    }
}

// ---------------- conv: FFT -> xV -> IFFT, in place on zx ----------------
__global__ void __launch_bounds__(512, 2) k_conv(float2* __restrict__ zx,
                                                 const float2* __restrict__ V,
                                                 const float2* __restrict__ tw)
{
    __shared__ float2 Z[8192];
    int blk = blockIdx.x;            // bh*32 + p
    int bh = blk >> 5, p = blk & 31, h = bh & 15;
    float2* zc = zx + (size_t)blk * 4096;
    int t = threadIdx.x;
    #pragma unroll
    for (int i = 0; i < 8; ++i) {
        int idx = i * 512 + t;
        Z[sw(idx)] = zc[idx];
        Z[sw(idx + 4096)] = make_float2(0.0f, 0.0f);    // zero-pad to 8192
    }
    __syncthreads();
    fft8192_lds<false>(Z, tw);
    const float2* V0 = V + (size_t)(h * 64 + 2 * p) * 4104;
    const float2* V1 = V0 + 4104;
    for (int k = t; k <= 4096; k += 512) {
        int km = (8192 - k) & 8191;
        float2 z1 = Z[sw(k)], z2 = Z[sw(km)];
        float zr1 = z1.x, zi1 = z1.y;
        float zr2 = z2.x, zi2 = -z2.y;
        float x0r = 0.5f * (zr1 + zr2), x0i = 0.5f * (zi1 + zi2);
        float x1r = 0.5f * (zi1 - zi2), x1i = -0.5f * (zr1 - zr2);
        float2 v0 = V0[k], v1 = V1[k];
        float y0r = v0.x * x0r - v0.y * x0i, y0i = v0.x * x0i + v0.y * x0r;
        float y1r = v1.x * x1r - v1.y * x1i, y1i = v1.x * x1i + v1.y * x1r;
        Z[sw(k)] = make_float2(y0r - y1i, y0i + y1r);   // Y0 + i*Y1
        if (k > 0 && k < 4096)                          // conj at mirror bin
            Z[sw(km)] = make_float2(y0r + y1i, y1r - y0i);
    }
    __syncthreads();
    fft8192_lds<true>(Z, tw);
    #pragma unroll
    for (int i = 0; i < 8; ++i) {
        int idx = i * 512 + t;
        zc[idx] = Z[sw(idx)];                           // keep first 4096 lags
    }
}

// ---------------- unpack: float2[bh][p][r] -> out(b,h,r,d) ----------------
__global__ void __launch_bounds__(256) k_unpack_out(const float2* __restrict__ zo,
                                                    float* __restrict__ out)
{
    int blk = blockIdx.x;
    int bh = blk >> 7, rt = blk & 127, r0 = rt << 5;
    __shared__ float tile[64][33];
    const float2* zp = zo + (size_t)bh * 32 * 4096;
    int tid = threadIdx.x;
    #pragma unroll
    for (int i = 0; i < 4; ++i) {
        int idx = i * 256 + tid;
        int p = idx >> 5, rr = idx & 31;
        float2 v = zp[(size_t)p * 4096 + r0 + rr];
        tile[2 * p][rr] = v.x; tile[2 * p + 1][rr] = v.y;
    }
    __syncthreads();
    float* op = out + (size_t)bh * 4096 * 64;
    #pragma unroll
    for (int i = 0; i < 8; ++i) {
        int idx = i * 256 + tid;
        int rr = idx >> 6, d = idx & 63;
        op[(size_t)(r0 + rr) * 64 + d] = tile[d][rr];
    }
}

extern "C" void kernel_launch(void* const* d_in, const int* in_sizes, int n_in,
                              void* d_out, int out_size, void* d_ws, size_t ws_size,
                              hipStream_t stream)
{
    (void)in_sizes; (void)n_in; (void)out_size;
    const float* x   = (const float*)d_in[0];
    const float* w0  = (const float*)d_in[1];
    const float* b0  = (const float*)d_in[2];
    const float* g1  = (const float*)d_in[3];
    const float* be1 = (const float*)d_in[4];
    const float* w1  = (const float*)d_in[5];
    const float* b1  = (const float*)d_in[6];
    const float* g2  = (const float*)d_in[7];
    const float* be2 = (const float*)d_in[8];
    const float* w2  = (const float*)d_in[9];
    const float* b2  = (const float*)d_in[10];
    const float* g3  = (const float*)d_in[11];
    const float* be3 = (const float*)d_in[12];
    const float* w3  = (const float*)d_in[13];
    const float* b3  = (const float*)d_in[14];
    float* out = (float*)d_out;
    char* ws = (char*)d_ws;
    if (ws_size < WS_NEED) return;

    float2* tw = (float2*)(ws + OFF_TW);
    float2* V  = (float2*)(ws + OFF_V);
    float2* aT = (float2*)(ws + OFF_AT);
    float2* zx = (float2*)(ws + OFF_ZX);

    k_init_tw<<<16, 256, 0, stream>>>(tw);
    k_dpb<<<2048, 256, 0, stream>>>(w0, b0, g1, be1, w1, b1, g2, be2,
                                    w2, b2, g3, be3, w3, b3, (float*)aT);
    k_vfft<<<512, 512, 0, stream>>>(aT, tw, V);
    k_pack_x<<<16384, 256, 0, stream>>>(x, zx);
    k_conv<<<4096, 512, 0, stream>>>(zx, V, tw);
    k_unpack_out<<<16384, 256, 0, stream>>>((const float2*)zx, out);
}

// Round 4
// 779.528 us; speedup vs baseline: 1.1089x; 1.1089x over previous
//
#include <hip/hip_runtime.h>
#include <math.h>

// ---------------- workspace layout ----------------
static const size_t OFF_TW = 0;
static const size_t OFF_V  = 32768;
static const size_t OFF_AT = OFF_V  + (size_t)16 * 64 * 4104 * 8;
static const size_t OFF_ZX = OFF_AT + (size_t)16 * 32 * 8192 * 8;
static const size_t WS_NEED = OFF_ZX + (size_t)128 * 32 * 4096 * 8;

// ---------------- twiddle init ----------------
__global__ void __launch_bounds__(256) k_init_tw(float2* __restrict__ tw)
{
    int k = blockIdx.x * 256 + threadIdx.x;
    if (k < 4096) {
        double a = (double)k * (3.14159265358979323846 / 4096.0);
        tw[k] = make_float2((float)cos(a), (float)(-sin(a)));
    }
}

// ---------------- dpb MLP: lane per evaluation row ----------------
// All loops that index the per-thread arrays are FULLY unrolled so every
// array access has a compile-time index -> arrays live in VGPRs, not scratch.
__device__ __forceinline__ void ln_relu_arr(float* b,
                                            const float* __restrict__ g,
                                            const float* __restrict__ be)
{
    float s0 = 0, s1 = 0, s2 = 0, s3 = 0;
    #pragma unroll
    for (int k = 0; k < 64; k += 4) {
        s0 += b[k]; s1 += b[k + 1]; s2 += b[k + 2]; s3 += b[k + 3];
    }
    float m = (s0 + s1 + s2 + s3) * (1.0f / 64.0f);
    float v0 = 0, v1 = 0, v2 = 0, v3 = 0;
    #pragma unroll
    for (int k = 0; k < 64; k += 4) {
        float c0 = b[k] - m, c1 = b[k + 1] - m, c2 = b[k + 2] - m, c3 = b[k + 3] - m;
        v0 = fmaf(c0, c0, v0); v1 = fmaf(c1, c1, v1);
        v2 = fmaf(c2, c2, v2); v3 = fmaf(c3, c3, v3);
    }
    float inv = rsqrtf((v0 + v1 + v2 + v3) * (1.0f / 64.0f) + 1e-5f);
    #pragma unroll
    for (int k = 0; k < 64; ++k)
        b[k] = fmaxf(fmaf((b[k] - m) * inv, g[k], be[k]), 0.0f);
}

__device__ __forceinline__ void matmul64(const float* b, float* o,
                                         const float* __restrict__ w,
                                         const float* __restrict__ bias)
{
    #pragma unroll
    for (int j = 0; j < 64; ++j) o[j] = bias[j];
    #pragma unroll
    for (int k = 0; k < 64; ++k) {
        float bk = b[k];
        const float* wr = w + (k << 6);
        #pragma unroll
        for (int j = 0; j < 64; ++j) o[j] = fmaf(bk, wr[j], o[j]);
    }
}

__global__ void __launch_bounds__(256) k_dpb(
    const float* __restrict__ w0,  const float* __restrict__ b0,
    const float* __restrict__ g1,  const float* __restrict__ be1,
    const float* __restrict__ w1,  const float* __restrict__ b1,
    const float* __restrict__ g2,  const float* __restrict__ be2,
    const float* __restrict__ w2,  const float* __restrict__ b2,
    const float* __restrict__ g3,  const float* __restrict__ be3,
    const float* __restrict__ w3,  const float* __restrict__ b3,
    float* __restrict__ aTf)
{
    int e  = blockIdx.x * 256 + threadIdx.x;
    int r  = e & 8191;
    int dd = e >> 13;
    const float scale = (float)(1.0 / 262080.0);
    float u;
    if (r == 0 || r == 4096) u = 0.0f;
    else if (r < 4096)       u = (float)((r - 1) * 64 + dd + 1) * scale;
    else                     u = -(float)(262080 - ((r - 4097) * 64 + dd)) * scale;

    float b[64], o[64];
    #pragma unroll
    for (int j = 0; j < 64; ++j) b[j] = fmaf(u, w0[j], b0[j]);

    ln_relu_arr(b, g1, be1);
    matmul64(b, o, w1, b1);
    ln_relu_arr(o, g2, be2);
    matmul64(o, b, w2, b2);
    ln_relu_arr(b, g3, be3);

    float f[16];
    #pragma unroll
    for (int j = 0; j < 16; ++j) f[j] = b3[j];
    #pragma unroll
    for (int k = 0; k < 64; ++k) {
        float bk = b[k];
        const float* wr = w3 + (k << 4);
        #pragma unroll
        for (int j = 0; j < 16; ++j) f[j] = fmaf(bk, wr[j], f[j]);
    }
    #pragma unroll
    for (int h = 0; h < 16; ++h) {
        size_t idx = ((size_t)((h << 5) + (dd >> 1)) * 8192 + r) * 2 + (dd & 1);
        aTf[idx] = f[h];
    }
}

// ---------------- LDS swizzle for float2[8192] ----------------
// sw(p) = p ^ ((p>>4)&15) ^ ((p>>8)&1): involution on [0,8192); keeps every
// access pattern in the FFT (contiguous fill, bit-reversed gather, stride-16
// writeback, radix-8 stage strides 16/128/1024, k<->8192-k pairing) at
// exactly 4 dwords/bank per wave64 ds_*_b64 == conflict-free.
__device__ __forceinline__ int sw(int a)
{
    return a ^ ((a >> 4) & 15) ^ ((a >> 8) & 1);
}

__device__ __forceinline__ float2 cmul(float2 a, float2 b)
{
    return make_float2(fmaf(a.x, b.x, -(a.y * b.y)), fmaf(a.x, b.y, a.y * b.x));
}

// multiply by forward twiddle (wr, wi); INV conjugates the twiddle
template<bool INV>
__device__ __forceinline__ float2 twm(float2 a, float wr, float wi)
{
    float i = INV ? -wi : wi;
    return make_float2(fmaf(a.x, wr, -(a.y * i)), fmaf(a.x, i, a.y * wr));
}

// ---------------- in-register 8-point DIT FFT ----------------
// input z in bit-reversed order, output natural order
// (structurally the first-3-stage prefix of the verified fft16)
template<bool INV>
__device__ __forceinline__ void fft8(float2* z)
{
    const float SQ = 0.70710678118654752440f;
    #pragma unroll
    for (int b = 0; b < 8; b += 2) {
        float2 u = z[b], t = z[b + 1];
        z[b]     = make_float2(u.x + t.x, u.y + t.y);
        z[b + 1] = make_float2(u.x - t.x, u.y - t.y);
    }
    const float w4r[2] = {1.0f, 0.0f};
    const float w4i[2] = {0.0f, -1.0f};
    #pragma unroll
    for (int b = 0; b < 8; b += 4) {
        #pragma unroll
        for (int j = 0; j < 2; ++j) {
            float2 u = z[b + j];
            float2 t = twm<INV>(z[b + j + 2], w4r[j], w4i[j]);
            z[b + j]     = make_float2(u.x + t.x, u.y + t.y);
            z[b + j + 2] = make_float2(u.x - t.x, u.y - t.y);
        }
    }
    const float w8r[4] = {1.0f, SQ, 0.0f, -SQ};
    const float w8i[4] = {0.0f, -SQ, -1.0f, -SQ};
    #pragma unroll
    for (int j = 0; j < 4; ++j) {
        float2 u = z[j];
        float2 t = twm<INV>(z[j + 4], w8r[j], w8i[j]);
        z[j]     = make_float2(u.x + t.x, u.y + t.y);
        z[j + 4] = make_float2(u.x - t.x, u.y - t.y);
    }
}

// ---------------- radix-8 LDS butterfly ----------------
// Fuses 3 radix-2 DIT stages (spans L,2L,4L):
//   out_q = sum_u v[rev3(u)] * W_{8L}^{j*u} * W_8^{q*u}
// tw index scale s must satisfy 8*L*s == 8192.
// (stage A: L=16,s=64; stage B: L=128,s=8; stage C: L=1024,s=1)
// Peak live state ~ z[8] + 7 twiddles + addr[8] ~= 45 floats -> fits the
// 64-VGPR cap needed for 2-block/CU co-residency (r16 needed ~90 -> spilled).
// Max direct tw load = 4*j*s <= 4092 < 4096, table unchanged.
template<bool INV>
__device__ __forceinline__ void r8(float2* __restrict__ Z, int base, int j, int L, int s,
                                   const float2* __restrict__ tw)
{
    int addr[8];
    #pragma unroll
    for (int m = 0; m < 8; ++m) addr[m] = sw(base + j + L * m);
    float2 t1 = tw[j * s], t2 = tw[2 * j * s], t4 = tw[4 * j * s];
    if (INV) { t1.y = -t1.y; t2.y = -t2.y; t4.y = -t4.y; }
    float2 T3 = cmul(t1, t2), T5 = cmul(t1, t4), T6 = cmul(t2, t4), T7 = cmul(T3, t4);
    // rv3 = {0,4,2,6,1,5,3,7}: z[m] = Z[addr[m]] * W^{j*s*rev3(m)}
    float2 z[8];
    z[0] = Z[addr[0]];
    z[1] = cmul(Z[addr[1]], t4);
    z[2] = cmul(Z[addr[2]], t2);
    z[3] = cmul(Z[addr[3]], T6);
    z[4] = cmul(Z[addr[4]], t1);
    z[5] = cmul(Z[addr[5]], T5);
    z[6] = cmul(Z[addr[6]], T3);
    z[7] = cmul(Z[addr[7]], T7);
    fft8<INV>(z);
    #pragma unroll
    for (int q = 0; q < 8; ++q) Z[addr[q]] = z[q];
}

// ---------------- first 4 stages in registers (16 pts/thread) ----------------
template<int L, bool INV>
__device__ __forceinline__ void reg_stage16(float* xr, float* xi,
                                            const float2* __restrict__ tw)
{
    #pragma unroll
    for (int b = 0; b < 16; b += 2 * L) {
        #pragma unroll
        for (int j = 0; j < L; ++j) {
            float2 w = tw[j * (4096 / L)];
            float wr = w.x, wi = INV ? -w.y : w.y;
            int i0 = b + j, i1 = b + j + L;
            float tr = xr[i1] * wr - xi[i1] * wi;
            float ti = xr[i1] * wi + xi[i1] * wr;
            xr[i1] = xr[i0] - tr; xi[i1] = xi[i0] - ti;
            xr[i0] += tr;         xi[i0] += ti;
        }
    }
}

// ---------------- 8192-pt complex FFT: natural in/out, 512 threads ----------
// 13 radix-2 stages = reg fft16 (spans 1..8) + r8 (16..64) + r8 (128..512)
//                   + r8 (1024..4096).
// Caller must __syncthreads() after populating Z and before calling.
template<bool INV>
__device__ __forceinline__ void fft8192_lds(float2* __restrict__ Z,
                                            const float2* __restrict__ tw)
{
    const int t  = threadIdx.x;                       // 512 threads
    const int r9 = (int)(__brev((unsigned)t) >> 23);  // rev9(t)
    float xr[16], xi[16];
    #pragma unroll
    for (int i = 0; i < 16; ++i) {
        int r4 = (int)(__brev((unsigned)i) >> 28);    // rev4(i)
        float2 v = Z[sw((r4 << 9) | r9)];             // rev13(16t+i)
        xr[i] = v.x; xi[i] = v.y;
    }
    __syncthreads();
    reg_stage16<1, INV>(xr, xi, tw);
    reg_stage16<2, INV>(xr, xi, tw);
    reg_stage16<4, INV>(xr, xi, tw);
    reg_stage16<8, INV>(xr, xi, tw);
    #pragma unroll
    for (int i = 0; i < 16; ++i) Z[sw(16 * t + i)] = make_float2(xr[i], xi[i]);
    __syncthreads();
    // stage A: spans 16..64, 64 groups of 128
    r8<INV>(Z, (t >> 4) * 128, t & 15, 16, 64, tw);
    r8<INV>(Z, ((t + 512) >> 4) * 128, t & 15, 16, 64, tw);
    __syncthreads();
    // stage B: spans 128..512, 8 groups of 1024
    r8<INV>(Z, (t >> 7) * 1024, t & 127, 128, 8, tw);
    r8<INV>(Z, ((t + 512) >> 7) * 1024, (t + 512) & 127, 128, 8, tw);
    __syncthreads();
    // stage C: spans 1024..4096, single group of 8192
    r8<INV>(Z, 0, t, 1024, 1, tw);
    r8<INV>(Z, 0, t + 512, 1024, 1, tw);
    __syncthreads();
}

// ---------------- V = rfft(a) / 8192, d-pairs packed ----------------
// launch_bounds note (empirical, HIP/CUDA minBlocks semantics):
// (512,4) -> compiler caps VGPR at 64 -> two 512-thr/64KiB blocks co-reside
// (43% occupancy, round 2). r16 spilled at that cap; r8 fits (~45 live).
__global__ void __launch_bounds__(512, 4) k_vfft(const float2* __restrict__ aT,
                                                 const float2* __restrict__ tw,
                                                 float2* __restrict__ V)
{
    __shared__ float2 Z[8192];
    int blk = blockIdx.x;         // h*32 + p
    int h = blk >> 5, p = blk & 31;
    const float2* ac = aT + (size_t)(h * 32 + p) * 8192;
    int t = threadIdx.x;
    #pragma unroll
    for (int i = 0; i < 16; ++i) {
        int idx = i * 512 + t;
        Z[sw(idx)] = ac[idx];
    }
    __syncthreads();
    fft8192_lds<false>(Z, tw);
    const float s = 1.0f / 8192.0f;
    float2* V0 = V + (size_t)(h * 64 + 2 * p) * 4104;
    float2* V1 = V0 + 4104;
    for (int k = t; k <= 4096; k += 512) {
        int km = (8192 - k) & 8191;
        float2 z1 = Z[sw(k)], z2 = Z[sw(km)];
        float zr1 = z1.x, zi1 = z1.y;
        float zr2 = z2.x, zi2 = -z2.y;
        float a0r = 0.5f * (zr1 + zr2), a0i = 0.5f * (zi1 + zi2);
        float a1r = 0.5f * (zi1 - zi2), a1i = -0.5f * (zr1 - zr2);
        V0[k] = make_float2(a0r * s, a0i * s);
        V1[k] = make_float2(a1r * s, a1i * s);
    }
}

// ---------------- pack x: (b,h,r,d) -> float2[bh][p][r] ----------------
__global__ void __launch_bounds__(256) k_pack_x(const float* __restrict__ x,
                                                float2* __restrict__ zx)
{
    int blk = blockIdx.x;
    int bh = blk >> 7, rt = blk & 127, r0 = rt << 5;
    __shared__ float tile[64][33];
    const float* xp = x + (size_t)bh * 4096 * 64;
    int tid = threadIdx.x;
    #pragma unroll
    for (int i = 0; i < 8; ++i) {
        int idx = i * 256 + tid;
        int rr = idx >> 6, d = idx & 63;
        tile[d][rr] = xp[(size_t)(r0 + rr) * 64 + d];
    }
    __syncthreads();
    float2* zp = zx + (size_t)bh * 32 * 4096;
    #pragma unroll
    for (int i = 0; i < 4; ++i) {
        int idx = i * 256 + tid;
        int p = idx >> 5, rr = idx & 31;
        zp[(size_t)p * 4096 + r0 + rr] = make_float2(tile[2 * p][rr], tile[2 * p + 1][rr]);
    }
}

// ---------------- conv: FFT -> xV -> IFFT, in place on zx ----------------
__global__ void __launch_bounds__(512, 4) k_conv(float2* __restrict__ zx,
                                                 const float2* __restrict__ V,
                                                 const float2* __restrict__ tw)
{
    __shared__ float2 Z[8192];
    int blk = blockIdx.x;            // bh*32 + p
    int bh = blk >> 5, p = blk & 31, h = bh & 15;
    float2* zc = zx + (size_t)blk * 4096;
    int t = threadIdx.x;
    #pragma unroll
    for (int i = 0; i < 8; ++i) {
        int idx = i * 512 + t;
        Z[sw(idx)] = zc[idx];
        Z[sw(idx + 4096)] = make_float2(0.0f, 0.0f);    // zero-pad to 8192
    }
    __syncthreads();
    fft8192_lds<false>(Z, tw);
    const float2* V0 = V + (size_t)(h * 64 + 2 * p) * 4104;
    const float2* V1 = V0 + 4104;
    for (int k = t; k <= 4096; k += 512) {
        int km = (8192 - k) & 8191;
        float2 z1 = Z[sw(k)], z2 = Z[sw(km)];
        float zr1 = z1.x, zi1 = z1.y;
        float zr2 = z2.x, zi2 = -z2.y;
        float x0r = 0.5f * (zr1 + zr2), x0i = 0.5f * (zi1 + zi2);
        float x1r = 0.5f * (zi1 - zi2), x1i = -0.5f * (zr1 - zr2);
        float2 v0 = V0[k], v1 = V1[k];
        float y0r = v0.x * x0r - v0.y * x0i, y0i = v0.x * x0i + v0.y * x0r;
        float y1r = v1.x * x1r - v1.y * x1i, y1i = v1.x * x1i + v1.y * x1r;
        Z[sw(k)] = make_float2(y0r - y1i, y0i + y1r);   // Y0 + i*Y1
        if (k > 0 && k < 4096)                          // conj at mirror bin
            Z[sw(km)] = make_float2(y0r + y1i, y1r - y0i);
    }
    __syncthreads();
    fft8192_lds<true>(Z, tw);
    #pragma unroll
    for (int i = 0; i < 8; ++i) {
        int idx = i * 512 + t;
        zc[idx] = Z[sw(idx)];                           // keep first 4096 lags
    }
}

// ---------------- unpack: float2[bh][p][r] -> out(b,h,r,d) ----------------
__global__ void __launch_bounds__(256) k_unpack_out(const float2* __restrict__ zo,
                                                    float* __restrict__ out)
{
    int blk = blockIdx.x;
    int bh = blk >> 7, rt = blk & 127, r0 = rt << 5;
    __shared__ float tile[64][33];
    const float2* zp = zo + (size_t)bh * 32 * 4096;
    int tid = threadIdx.x;
    #pragma unroll
    for (int i = 0; i < 4; ++i) {
        int idx = i * 256 + tid;
        int p = idx >> 5, rr = idx & 31;
        float2 v = zp[(size_t)p * 4096 + r0 + rr];
        tile[2 * p][rr] = v.x; tile[2 * p + 1][rr] = v.y;
    }
    __syncthreads();
    float* op = out + (size_t)bh * 4096 * 64;
    #pragma unroll
    for (int i = 0; i < 8; ++i) {
        int idx = i * 256 + tid;
        int rr = idx >> 6, d = idx & 63;
        op[(size_t)(r0 + rr) * 64 + d] = tile[d][rr];
    }
}

extern "C" void kernel_launch(void* const* d_in, const int* in_sizes, int n_in,
                              void* d_out, int out_size, void* d_ws, size_t ws_size,
                              hipStream_t stream)
{
    (void)in_sizes; (void)n_in; (void)out_size;
    const float* x   = (const float*)d_in[0];
    const float* w0  = (const float*)d_in[1];
    const float* b0  = (const float*)d_in[2];
    const float* g1  = (const float*)d_in[3];
    const float* be1 = (const float*)d_in[4];
    const float* w1  = (const float*)d_in[5];
    const float* b1  = (const float*)d_in[6];
    const float* g2  = (const float*)d_in[7];
    const float* be2 = (const float*)d_in[8];
    const float* w2  = (const float*)d_in[9];
    const float* b2  = (const float*)d_in[10];
    const float* g3  = (const float*)d_in[11];
    const float* be3 = (const float*)d_in[12];
    const float* w3  = (const float*)d_in[13];
    const float* b3  = (const float*)d_in[14];
    float* out = (float*)d_out;
    char* ws = (char*)d_ws;
    if (ws_size < WS_NEED) return;

    float2* tw = (float2*)(ws + OFF_TW);
    float2* V  = (float2*)(ws + OFF_V);
    float2* aT = (float2*)(ws + OFF_AT);
    float2* zx = (float2*)(ws + OFF_ZX);

    k_init_tw<<<16, 256, 0, stream>>>(tw);
    k_dpb<<<2048, 256, 0, stream>>>(w0, b0, g1, be1, w1, b1, g2, be2,
                                    w2, b2, g3, be3, w3, b3, (float*)aT);
    k_vfft<<<512, 512, 0, stream>>>(aT, tw, V);
    k_pack_x<<<16384, 256, 0, stream>>>(x, zx);
    k_conv<<<4096, 512, 0, stream>>>(zx, V, tw);
    k_unpack_out<<<16384, 256, 0, stream>>>((const float2*)zx, out);
}

// Round 5
// 770.654 us; speedup vs baseline: 1.1217x; 1.0115x over previous
//
#include <hip/hip_runtime.h>
#include <math.h>

// ---------------- workspace layout ----------------
static const size_t OFF_TW = 0;
static const size_t OFF_V  = 32768;
static const size_t OFF_AT = OFF_V  + (size_t)16 * 64 * 4104 * 8;
static const size_t OFF_ZX = OFF_AT + (size_t)16 * 32 * 8192 * 8;
static const size_t WS_NEED = OFF_ZX + (size_t)128 * 32 * 4096 * 8;

// ---------------- twiddle init ----------------
__global__ void __launch_bounds__(256) k_init_tw(float2* __restrict__ tw)
{
    int k = blockIdx.x * 256 + threadIdx.x;
    if (k < 4096) {
        double a = (double)k * (3.14159265358979323846 / 4096.0);
        tw[k] = make_float2((float)cos(a), (float)(-sin(a)));
    }
}

// ---------------- dpb MLP: lane per evaluation row ----------------
// All loops that index the per-thread arrays are FULLY unrolled so every
// array access has a compile-time index -> arrays live in VGPRs, not scratch.
__device__ __forceinline__ void ln_relu_arr(float* b,
                                            const float* __restrict__ g,
                                            const float* __restrict__ be)
{
    float s0 = 0, s1 = 0, s2 = 0, s3 = 0;
    #pragma unroll
    for (int k = 0; k < 64; k += 4) {
        s0 += b[k]; s1 += b[k + 1]; s2 += b[k + 2]; s3 += b[k + 3];
    }
    float m = (s0 + s1 + s2 + s3) * (1.0f / 64.0f);
    float v0 = 0, v1 = 0, v2 = 0, v3 = 0;
    #pragma unroll
    for (int k = 0; k < 64; k += 4) {
        float c0 = b[k] - m, c1 = b[k + 1] - m, c2 = b[k + 2] - m, c3 = b[k + 3] - m;
        v0 = fmaf(c0, c0, v0); v1 = fmaf(c1, c1, v1);
        v2 = fmaf(c2, c2, v2); v3 = fmaf(c3, c3, v3);
    }
    float inv = rsqrtf((v0 + v1 + v2 + v3) * (1.0f / 64.0f) + 1e-5f);
    #pragma unroll
    for (int k = 0; k < 64; ++k)
        b[k] = fmaxf(fmaf((b[k] - m) * inv, g[k], be[k]), 0.0f);
}

__device__ __forceinline__ void matmul64(const float* b, float* o,
                                         const float* __restrict__ w,
                                         const float* __restrict__ bias)
{
    #pragma unroll
    for (int j = 0; j < 64; ++j) o[j] = bias[j];
    #pragma unroll
    for (int k = 0; k < 64; ++k) {
        float bk = b[k];
        const float* wr = w + (k << 6);
        #pragma unroll
        for (int j = 0; j < 64; ++j) o[j] = fmaf(bk, wr[j], o[j]);
    }
}

__global__ void __launch_bounds__(256) k_dpb(
    const float* __restrict__ w0,  const float* __restrict__ b0,
    const float* __restrict__ g1,  const float* __restrict__ be1,
    const float* __restrict__ w1,  const float* __restrict__ b1,
    const float* __restrict__ g2,  const float* __restrict__ be2,
    const float* __restrict__ w2,  const float* __restrict__ b2,
    const float* __restrict__ g3,  const float* __restrict__ be3,
    const float* __restrict__ w3,  const float* __restrict__ b3,
    float* __restrict__ aTf)
{
    int e  = blockIdx.x * 256 + threadIdx.x;
    int r  = e & 8191;
    int dd = e >> 13;
    const float scale = (float)(1.0 / 262080.0);
    float u;
    if (r == 0 || r == 4096) u = 0.0f;
    else if (r < 4096)       u = (float)((r - 1) * 64 + dd + 1) * scale;
    else                     u = -(float)(262080 - ((r - 4097) * 64 + dd)) * scale;

    float b[64], o[64];
    #pragma unroll
    for (int j = 0; j < 64; ++j) b[j] = fmaf(u, w0[j], b0[j]);

    ln_relu_arr(b, g1, be1);
    matmul64(b, o, w1, b1);
    ln_relu_arr(o, g2, be2);
    matmul64(o, b, w2, b2);
    ln_relu_arr(b, g3, be3);

    float f[16];
    #pragma unroll
    for (int j = 0; j < 16; ++j) f[j] = b3[j];
    #pragma unroll
    for (int k = 0; k < 64; ++k) {
        float bk = b[k];
        const float* wr = w3 + (k << 4);
        #pragma unroll
        for (int j = 0; j < 16; ++j) f[j] = fmaf(bk, wr[j], f[j]);
    }
    #pragma unroll
    for (int h = 0; h < 16; ++h) {
        size_t idx = ((size_t)((h << 5) + (dd >> 1)) * 8192 + r) * 2 + (dd & 1);
        aTf[idx] = f[h];
    }
}

// ---------------- LDS swizzle for float2[8192] ----------------
// sw(p) = p ^ ((p>>4)&15) ^ ((p>>8)&1): involution on [0,8192); XORs only
// bits 0-3 so it is closed within each 16-element block. Keeps every access
// pattern in the FFT (contiguous fill, bit-reversed gather, stride-8
// writeback, r8 strides 8/64/512, span-4096 radix-2, k<->8192-k pairing) at
// exactly 4 dwords/bank per wave64 ds_*_b64 == conflict-free minimum.
__device__ __forceinline__ int sw(int a)
{
    return a ^ ((a >> 4) & 15) ^ ((a >> 8) & 1);
}

__device__ __forceinline__ float2 cmul(float2 a, float2 b)
{
    return make_float2(fmaf(a.x, b.x, -(a.y * b.y)), fmaf(a.x, b.y, a.y * b.x));
}

// multiply by forward twiddle (wr, wi); INV conjugates the twiddle
template<bool INV>
__device__ __forceinline__ float2 twm(float2 a, float wr, float wi)
{
    float i = INV ? -wi : wi;
    return make_float2(fmaf(a.x, wr, -(a.y * i)), fmaf(a.x, i, a.y * wr));
}

// ---------------- in-register 8-point DIT FFT ----------------
// input z in bit-reversed order, output natural order
template<bool INV>
__device__ __forceinline__ void fft8(float2* z)
{
    const float SQ = 0.70710678118654752440f;
    #pragma unroll
    for (int b = 0; b < 8; b += 2) {
        float2 u = z[b], t = z[b + 1];
        z[b]     = make_float2(u.x + t.x, u.y + t.y);
        z[b + 1] = make_float2(u.x - t.x, u.y - t.y);
    }
    const float w4r[2] = {1.0f, 0.0f};
    const float w4i[2] = {0.0f, -1.0f};
    #pragma unroll
    for (int b = 0; b < 8; b += 4) {
        #pragma unroll
        for (int j = 0; j < 2; ++j) {
            float2 u = z[b + j];
            float2 t = twm<INV>(z[b + j + 2], w4r[j], w4i[j]);
            z[b + j]     = make_float2(u.x + t.x, u.y + t.y);
            z[b + j + 2] = make_float2(u.x - t.x, u.y - t.y);
        }
    }
    const float w8r[4] = {1.0f, SQ, 0.0f, -SQ};
    const float w8i[4] = {0.0f, -SQ, -1.0f, -SQ};
    #pragma unroll
    for (int j = 0; j < 4; ++j) {
        float2 u = z[j];
        float2 t = twm<INV>(z[j + 4], w8r[j], w8i[j]);
        z[j]     = make_float2(u.x + t.x, u.y + t.y);
        z[j + 4] = make_float2(u.x - t.x, u.y - t.y);
    }
}

// ---------------- radix-8 LDS butterfly ----------------
// Fuses 3 radix-2 DIT stages (spans L,2L,4L):
//   out_q = sum_u v[rev3(u)] * W_{8L}^{j*u} * W_8^{q*u}
// tw index scale s must satisfy 8*L*s == 8192.
// (stage A: L=8,s=128; stage B: L=64,s=16; stage C: L=512,s=2)
// Max direct tw load = 4*j*s <= 4088 < 4096, table unchanged.
template<bool INV>
__device__ __forceinline__ void r8(float2* __restrict__ Z, int base, int j, int L, int s,
                                   const float2* __restrict__ tw)
{
    int addr[8];
    #pragma unroll
    for (int m = 0; m < 8; ++m) addr[m] = sw(base + j + L * m);
    float2 t1 = tw[j * s], t2 = tw[2 * j * s], t4 = tw[4 * j * s];
    if (INV) { t1.y = -t1.y; t2.y = -t2.y; t4.y = -t4.y; }
    float2 T3 = cmul(t1, t2), T5 = cmul(t1, t4), T6 = cmul(t2, t4), T7 = cmul(T3, t4);
    // rv3 = {0,4,2,6,1,5,3,7}: z[m] = Z[addr[m]] * W^{j*s*rev3(m)}
    float2 z[8];
    z[0] = Z[addr[0]];
    z[1] = cmul(Z[addr[1]], t4);
    z[2] = cmul(Z[addr[2]], t2);
    z[3] = cmul(Z[addr[3]], T6);
    z[4] = cmul(Z[addr[4]], t1);
    z[5] = cmul(Z[addr[5]], T5);
    z[6] = cmul(Z[addr[6]], T3);
    z[7] = cmul(Z[addr[7]], T7);
    fft8<INV>(z);
    #pragma unroll
    for (int q = 0; q < 8; ++q) Z[addr[q]] = z[q];
}

// ---------------- first 3 stages in registers (8 pts/thread) ----------------
template<int L, bool INV>
__device__ __forceinline__ void reg_stage8(float* xr, float* xi,
                                           const float2* __restrict__ tw)
{
    #pragma unroll
    for (int b = 0; b < 8; b += 2 * L) {
        #pragma unroll
        for (int j = 0; j < L; ++j) {
            float2 w = tw[j * (4096 / L)];
            float wr = w.x, wi = INV ? -w.y : w.y;
            int i0 = b + j, i1 = b + j + L;
            float tr = xr[i1] * wr - xi[i1] * wi;
            float ti = xr[i1] * wi + xi[i1] * wr;
            xr[i1] = xr[i0] - tr; xi[i1] = xi[i0] - ti;
            xr[i0] += tr;         xi[i0] += ti;
        }
    }
}

// ---------------- 8192-pt complex FFT: natural in/out, 1024 threads --------
// 13 radix-2 stages = reg fft8 (spans 1..4) + r8 (8..32) + r8 (64..256)
//                   + r8 (512..2048) + radix-2 (4096). All 1024 threads are
// fully occupied in every stage (an r16 final stage would idle half).
// PAD=true: input is zero above index 4095. In bit-reversed DIT layout the
// zero values land exactly at odd positions, so stage 1 (twiddle W^0) is
// out0 = out1 = in0: skip the stage, load 4 values, duplicate. Caller then
// need not zero-fill the upper LDS half at all.
// Caller must __syncthreads() after populating Z and before calling.
template<bool INV, bool PAD>
__device__ __forceinline__ void fft8192_lds(float2* __restrict__ Z,
                                            const float2* __restrict__ tw)
{
    const int t   = threadIdx.x;                       // 1024 threads
    const int r10 = (int)(__brev((unsigned)t) >> 22);  // rev10(t)
    float xr[8], xi[8];
    if (PAD) {
        #pragma unroll
        for (int i = 0; i < 8; i += 2) {
            int r3 = (int)(__brev((unsigned)i) >> 29); // rev3(i) < 4 for even i
            float2 v = Z[sw((r3 << 10) | r10)];        // natural idx < 4096
            xr[i] = v.x; xi[i] = v.y;
            xr[i + 1] = v.x; xi[i + 1] = v.y;          // stage-1 output (pair is 0)
        }
    } else {
        #pragma unroll
        for (int i = 0; i < 8; ++i) {
            int r3 = (int)(__brev((unsigned)i) >> 29); // rev3(i)
            float2 v = Z[sw((r3 << 10) | r10)];        // rev13(8t+i)
            xr[i] = v.x; xi[i] = v.y;
        }
    }
    __syncthreads();
    if (!PAD) reg_stage8<1, INV>(xr, xi, tw);
    reg_stage8<2, INV>(xr, xi, tw);
    reg_stage8<4, INV>(xr, xi, tw);
    #pragma unroll
    for (int i = 0; i < 8; ++i) Z[sw(8 * t + i)] = make_float2(xr[i], xi[i]);
    __syncthreads();
    // stage A: spans 8..32, 128 groups of 64
    r8<INV>(Z, (t >> 3) * 64, t & 7, 8, 128, tw);
    __syncthreads();
    // stage B: spans 64..256, 16 groups of 512
    r8<INV>(Z, (t >> 6) * 512, t & 63, 64, 16, tw);
    __syncthreads();
    // stage C: spans 512..2048, 2 groups of 4096
    r8<INV>(Z, (t >> 9) * 4096, t & 511, 512, 2, tw);
    __syncthreads();
    // stage D: final radix-2, span 4096 (4 butterflies/thread)
    #pragma unroll
    for (int m = 0; m < 4; ++m) {
        int k = t + 1024 * m;
        float2 w = tw[k];
        float wi = INV ? -w.y : w.y;
        int aL = sw(k), aH = sw(k + 4096);
        float2 u = Z[aL], v = Z[aH];
        float tr = fmaf(v.x, w.x, -(v.y * wi));
        float ti = fmaf(v.x, wi, v.y * w.x);
        Z[aL] = make_float2(u.x + tr, u.y + ti);
        Z[aH] = make_float2(u.x - tr, u.y - ti);
    }
    __syncthreads();
}

// ---------------- V = rfft(a) / 8192, d-pairs packed ----------------
// 1024-thr block = 16 waves/CU at 1 block (LDS 64 KiB) -> VGPR cap 128,
// which the r8-based FFT fits WITHOUT spilling (the 512-thr/2-block design
// needed VGPR<=64 and spilled ~550 MB/dispatch; 1-block/512-thr was 23% occ).
__global__ void __launch_bounds__(1024, 1) k_vfft(const float2* __restrict__ aT,
                                                  const float2* __restrict__ tw,
                                                  float2* __restrict__ V)
{
    __shared__ float2 Z[8192];
    int blk = blockIdx.x;         // h*32 + p
    int h = blk >> 5, p = blk & 31;
    const float2* ac = aT + (size_t)(h * 32 + p) * 8192;
    int t = threadIdx.x;
    #pragma unroll
    for (int i = 0; i < 8; ++i) {
        int idx = i * 1024 + t;
        Z[sw(idx)] = ac[idx];
    }
    __syncthreads();
    fft8192_lds<false, false>(Z, tw);
    const float s = 1.0f / 8192.0f;
    float2* V0 = V + (size_t)(h * 64 + 2 * p) * 4104;
    float2* V1 = V0 + 4104;
    for (int k = t; k <= 4096; k += 1024) {
        int km = (8192 - k) & 8191;
        float2 z1 = Z[sw(k)], z2 = Z[sw(km)];
        float zr1 = z1.x, zi1 = z1.y;
        float zr2 = z2.x, zi2 = -z2.y;
        float a0r = 0.5f * (zr1 + zr2), a0i = 0.5f * (zi1 + zi2);
        float a1r = 0.5f * (zi1 - zi2), a1i = -0.5f * (zr1 - zr2);
        V0[k] = make_float2(a0r * s, a0i * s);
        V1[k] = make_float2(a1r * s, a1i * s);
    }
}

// ---------------- pack x: (b,h,r,d) -> float2[bh][p][r] ----------------
__global__ void __launch_bounds__(256) k_pack_x(const float* __restrict__ x,
                                                float2* __restrict__ zx)
{
    int blk = blockIdx.x;
    int bh = blk >> 7, rt = blk & 127, r0 = rt << 5;
    __shared__ float tile[64][33];
    const float* xp = x + (size_t)bh * 4096 * 64;
    int tid = threadIdx.x;
    #pragma unroll
    for (int i = 0; i < 8; ++i) {
        int idx = i * 256 + tid;
        int rr = idx >> 6, d = idx & 63;
        tile[d][rr] = xp[(size_t)(r0 + rr) * 64 + d];
    }
    __syncthreads();
    float2* zp = zx + (size_t)bh * 32 * 4096;
    #pragma unroll
    for (int i = 0; i < 4; ++i) {
        int idx = i * 256 + tid;
        int p = idx >> 5, rr = idx & 31;
        zp[(size_t)p * 4096 + r0 + rr] = make_float2(tile[2 * p][rr], tile[2 * p + 1][rr]);
    }
}

// ---------------- conv: FFT -> xV -> IFFT, in place on zx ----------------
__global__ void __launch_bounds__(1024, 1) k_conv(float2* __restrict__ zx,
                                                  const float2* __restrict__ V,
                                                  const float2* __restrict__ tw)
{
    __shared__ float2 Z[8192];
    int blk = blockIdx.x;            // bh*32 + p
    int bh = blk >> 5, p = blk & 31, h = bh & 15;
    float2* zc = zx + (size_t)blk * 4096;
    int t = threadIdx.x;
    #pragma unroll
    for (int i = 0; i < 4; ++i) {
        int idx = i * 1024 + t;
        Z[sw(idx)] = zc[idx];        // no zero-fill needed: PAD gather skips it
    }
    __syncthreads();
    fft8192_lds<false, true>(Z, tw);
    const float2* V0 = V + (size_t)(h * 64 + 2 * p) * 4104;
    const float2* V1 = V0 + 4104;
    for (int k = t; k <= 4096; k += 1024) {
        int km = (8192 - k) & 8191;
        float2 z1 = Z[sw(k)], z2 = Z[sw(km)];
        float zr1 = z1.x, zi1 = z1.y;
        float zr2 = z2.x, zi2 = -z2.y;
        float x0r = 0.5f * (zr1 + zr2), x0i = 0.5f * (zi1 + zi2);
        float x1r = 0.5f * (zi1 - zi2), x1i = -0.5f * (zr1 - zr2);
        float2 v0 = V0[k], v1 = V1[k];
        float y0r = v0.x * x0r - v0.y * x0i, y0i = v0.x * x0i + v0.y * x0r;
        float y1r = v1.x * x1r - v1.y * x1i, y1i = v1.x * x1i + v1.y * x1r;
        Z[sw(k)] = make_float2(y0r - y1i, y0i + y1r);   // Y0 + i*Y1
        if (k > 0 && k < 4096)                          // conj at mirror bin
            Z[sw(km)] = make_float2(y0r + y1i, y1r - y0i);
    }
    __syncthreads();
    fft8192_lds<true, false>(Z, tw);
    #pragma unroll
    for (int i = 0; i < 4; ++i) {
        int idx = i * 1024 + t;
        zc[idx] = Z[sw(idx)];                           // keep first 4096 lags
    }
}

// ---------------- unpack: float2[bh][p][r] -> out(b,h,r,d) ----------------
__global__ void __launch_bounds__(256) k_unpack_out(const float2* __restrict__ zo,
                                                    float* __restrict__ out)
{
    int blk = blockIdx.x;
    int bh = blk >> 7, rt = blk & 127, r0 = rt << 5;
    __shared__ float tile[64][33];
    const float2* zp = zo + (size_t)bh * 32 * 4096;
    int tid = threadIdx.x;
    #pragma unroll
    for (int i = 0; i < 4; ++i) {
        int idx = i * 256 + tid;
        int p = idx >> 5, rr = idx & 31;
        float2 v = zp[(size_t)p * 4096 + r0 + rr];
        tile[2 * p][rr] = v.x; tile[2 * p + 1][rr] = v.y;
    }
    __syncthreads();
    float* op = out + (size_t)bh * 4096 * 64;
    #pragma unroll
    for (int i = 0; i < 8; ++i) {
        int idx = i * 256 + tid;
        int rr = idx >> 6, d = idx & 63;
        op[(size_t)(r0 + rr) * 64 + d] = tile[d][rr];
    }
}

extern "C" void kernel_launch(void* const* d_in, const int* in_sizes, int n_in,
                              void* d_out, int out_size, void* d_ws, size_t ws_size,
                              hipStream_t stream)
{
    (void)in_sizes; (void)n_in; (void)out_size;
    const float* x   = (const float*)d_in[0];
    const float* w0  = (const float*)d_in[1];
    const float* b0  = (const float*)d_in[2];
    const float* g1  = (const float*)d_in[3];
    const float* be1 = (const float*)d_in[4];
    const float* w1  = (const float*)d_in[5];
    const float* b1  = (const float*)d_in[6];
    const float* g2  = (const float*)d_in[7];
    const float* be2 = (const float*)d_in[8];
    const float* w2  = (const float*)d_in[9];
    const float* b2  = (const float*)d_in[10];
    const float* g3  = (const float*)d_in[11];
    const float* be3 = (const float*)d_in[12];
    const float* w3  = (const float*)d_in[13];
    const float* b3  = (const float*)d_in[14];
    float* out = (float*)d_out;
    char* ws = (char*)d_ws;
    if (ws_size < WS_NEED) return;

    float2* tw = (float2*)(ws + OFF_TW);
    float2* V  = (float2*)(ws + OFF_V);
    float2* aT = (float2*)(ws + OFF_AT);
    float2* zx = (float2*)(ws + OFF_ZX);

    k_init_tw<<<16, 256, 0, stream>>>(tw);
    k_dpb<<<2048, 256, 0, stream>>>(w0, b0, g1, be1, w1, b1, g2, be2,
                                    w2, b2, g3, be3, w3, b3, (float*)aT);
    k_vfft<<<512, 1024, 0, stream>>>(aT, tw, V);
    k_pack_x<<<16384, 256, 0, stream>>>(x, zx);
    k_conv<<<4096, 1024, 0, stream>>>(zx, V, tw);
    k_unpack_out<<<16384, 256, 0, stream>>>((const float2*)zx, out);
}